// Round 1
// baseline (515.474 us; speedup 1.0000x reference)
//
#include <hip/hip_runtime.h>
#include <math.h>

#define BB   16
#define SS   1024
#define PP   1024
#define DD   128
#define HH   8
#define HDD  16
#define MSS  32
#define EE   524288
#define NROW (BB*SS)   /* 16384 */
#define NCOL (BB*PP)   /* 16384 */

// C[M,N] = A[M,128] @ B[128,N]; block = N threads, 16 rows per block.
// A tile staged in LDS (broadcast reads), B rows read coalesced (L2-resident).
template<int N>
__global__ __launch_bounds__(N) void gemm16_kernel(const float* __restrict__ A,
                                                   const float* __restrict__ B,
                                                   float* __restrict__ C) {
    __shared__ float As[16 * 128];
    int t = threadIdx.x;
    const float* Arow = A + (size_t)blockIdx.x * 16 * 128;
    for (int i = t; i < 16 * 128; i += N) As[i] = Arow[i];
    __syncthreads();
    float acc[16];
#pragma unroll
    for (int i = 0; i < 16; i++) acc[i] = 0.f;
    for (int k = 0; k < 128; k++) {
        float bk = B[k * N + t];
#pragma unroll
        for (int i = 0; i < 16; i++) acc[i] = fmaf(As[i * 128 + k], bk, acc[i]);
    }
    float* Crow = C + (size_t)blockIdx.x * 16 * N + t;
#pragma unroll
    for (int i = 0; i < 16; i++) Crow[(size_t)i * N] = acc[i];
}

// One thread per (edge, head): q·k dot, score MLP, exp. Thread h==0 of each
// edge also writes row/col flat ids and bumps the CSR histogram counters.
__global__ __launch_bounds__(256) void edge_kernel(
        const float* __restrict__ qv1, const float* __restrict__ kv2,
        const int* __restrict__ b_idx, const int* __restrict__ s_idx,
        const int* __restrict__ p_idx, const float* __restrict__ w,
        const float* __restrict__ msW1, const float* __restrict__ msb1,
        const float* __restrict__ msW2, const float* __restrict__ msb2,
        float* __restrict__ el, int* __restrict__ rf, int* __restrict__ cf,
        int* __restrict__ cnt_row, int* __restrict__ cnt_col) {
    __shared__ float sW1[HH * 2 * MSS], sB1[HH * MSS], sW2[HH * MSS], sB2[HH];
    int t = threadIdx.x;
    for (int i = t; i < HH * 2 * MSS; i += 256) sW1[i] = msW1[i];
    for (int i = t; i < HH * MSS; i += 256) sB1[i] = msb1[i];
    for (int i = t; i < HH * MSS; i += 256) sW2[i] = msW2[i];
    if (t < HH) sB2[t] = msb2[t];
    __syncthreads();

    int gid = blockIdx.x * 256 + t;
    int e = gid >> 3;
    int h = gid & 7;
    int b = b_idx[e], s = s_idx[e], p = p_idx[e];
    int row = b * SS + s;
    int col = b * PP + p;

    const float4* qp = (const float4*)(qv1 + (size_t)row * 256 + h * 16);
    const float4* kp = (const float4*)(kv2 + (size_t)col * 256 + h * 16);
    float dot = 0.f;
#pragma unroll
    for (int j = 0; j < 4; j++) {
        float4 a = qp[j], k4 = kp[j];
        dot = fmaf(a.x, k4.x, dot);
        dot = fmaf(a.y, k4.y, dot);
        dot = fmaf(a.z, k4.z, dot);
        dot = fmaf(a.w, k4.w, dot);
    }
    float logit = dot * 0.25f;  // 1/sqrt(HD=16)
    float we = w[e];

    const float* w1a = sW1 + h * 2 * MSS;  // msW1[h][0][:]
    const float* w1b = w1a + MSS;          // msW1[h][1][:]
    const float* b1 = sB1 + h * MSS;
    const float* w2 = sW2 + h * MSS;
    float outv = sB2[h];
#pragma unroll
    for (int m = 0; m < MSS; m++) {
        float hid = fmaf(logit, w1a[m], fmaf(we, w1b[m], b1[m]));
        hid = fmaxf(hid, 0.f);
        outv = fmaf(hid, w2[m], outv);
    }
    float score = 10.0f * tanhf(outv);  // TANH_CLIP / TEMP
    el[(size_t)e * 8 + h] = expf(score);

    if (h == 0) {
        rf[e] = row;
        cf[e] = col;
        atomicAdd(&cnt_row[row], 1);
        atomicAdd(&cnt_col[col], 1);
    }
}

// Exclusive scan of 16384 counts -> offsets[16385]; also seeds cursors.
// blockIdx 0 = rows, 1 = cols. 1024 threads, 16 elements each.
__global__ __launch_bounds__(1024) void scan_kernel(const int* __restrict__ cnt,
                                                    int* __restrict__ offs,
                                                    int* __restrict__ cur) {
    const int n = NROW;
    const int* c = cnt + (size_t)blockIdx.x * n;
    int* o = offs + (size_t)blockIdx.x * (n + 1);
    int* cu = cur + (size_t)blockIdx.x * n;
    __shared__ int sdata[1024];
    int t = threadIdx.x;
    int base = t * 16;
    int loc[16];
    int run = 0;
#pragma unroll
    for (int i = 0; i < 16; i++) { loc[i] = run; run += c[base + i]; }
    sdata[t] = run;
    __syncthreads();
    for (int st = 1; st < 1024; st <<= 1) {
        int v = (t >= st) ? sdata[t - st] : 0;
        __syncthreads();
        sdata[t] += v;
        __syncthreads();
    }
    int excl = sdata[t] - run;
#pragma unroll
    for (int i = 0; i < 16; i++) {
        int val = excl + loc[i];
        o[base + i] = val;
        cu[base + i] = val;
    }
    if (t == 1023) o[n] = sdata[1023];
}

__global__ __launch_bounds__(256) void scatter_kernel(
        const int* __restrict__ rf, const int* __restrict__ cf,
        int* __restrict__ cur_row, int* __restrict__ cur_col,
        int* __restrict__ list_row, int* __restrict__ list_col) {
    int e = blockIdx.x * 256 + threadIdx.x;
    int r = rf[e], c = cf[e];
    int pr = atomicAdd(&cur_row[r], 1);
    list_row[pr] = e;
    int pc = atomicAdd(&cur_col[c], 1);
    list_col[pc] = e;
}

// One block (128 thr = H*HD) per group g: out[g,t] = sum_e el[e,h]*vals[other[e],t]
// normalized by the per-head denom (sum of el) at the end.
__global__ __launch_bounds__(128) void combine_kernel(
        const int* __restrict__ list, const int* __restrict__ offs,
        const float* __restrict__ el, const int* __restrict__ other,
        const float* __restrict__ vals, float* __restrict__ outp) {
    int g = blockIdx.x;
    int t = threadIdx.x;  // t = h*16 + hd
    int h = t >> 4;
    int start = offs[g], end = offs[g + 1];
    float acc = 0.f, den = 0.f;
    for (int i = start; i < end; i++) {
        int e = list[i];
        float ev = el[(size_t)e * 8 + h];
        int oi = other[e];
        float v = vals[(size_t)oi * 256 + t];
        acc = fmaf(ev, v, acc);
        den += ev;
    }
    outp[(size_t)g * 128 + t] = acc / (den + 1e-9f);
}

extern "C" void kernel_launch(void* const* d_in, const int* in_sizes, int n_in,
                              void* d_out, int out_size, void* d_ws, size_t ws_size,
                              hipStream_t stream) {
    const float* x1   = (const float*)d_in[0];
    const float* x2   = (const float*)d_in[1];
    const int* b_idx  = (const int*)d_in[2];
    const int* s_idx  = (const int*)d_in[3];
    const int* p_idx  = (const int*)d_in[4];
    const float* w    = (const float*)d_in[5];
    const float* Wqv1 = (const float*)d_in[6];
    const float* Wkv2 = (const float*)d_in[7];
    const float* Wo1  = (const float*)d_in[8];
    const float* Wo2  = (const float*)d_in[9];
    const float* msW1 = (const float*)d_in[10];
    const float* msb1 = (const float*)d_in[11];
    const float* msW2 = (const float*)d_in[12];
    const float* msb2 = (const float*)d_in[13];
    float* out = (float*)d_out;

    // Workspace layout (fp32 region then int region), ~73 MiB total.
    float* qv1 = (float*)d_ws;                       // 16384*256
    float* kv2 = qv1 + (size_t)NROW * 256;           // 16384*256
    float* el  = kv2 + (size_t)NCOL * 256;           // E*8
    float* row_heads = el + (size_t)EE * 8;          // 16384*128
    float* col_heads = row_heads + (size_t)NROW * 128;
    int* ip = (int*)(col_heads + (size_t)NCOL * 128);
    int* rf = ip;        ip += EE;
    int* cf = ip;        ip += EE;
    int* list_row = ip;  ip += EE;
    int* list_col = ip;  ip += EE;
    int* cnt = ip;       ip += 2 * NROW;        // cnt_row | cnt_col
    int* offs = ip;      ip += 2 * (NROW + 1);  // offs_row | offs_col
    int* cur = ip;       ip += 2 * NROW;        // cur_row | cur_col

    hipMemsetAsync(cnt, 0, 2 * NROW * sizeof(int), stream);

    gemm16_kernel<256><<<NROW / 16, 256, 0, stream>>>(x1, Wqv1, qv1);
    gemm16_kernel<256><<<NCOL / 16, 256, 0, stream>>>(x2, Wkv2, kv2);

    edge_kernel<<<(EE * 8) / 256, 256, 0, stream>>>(
        qv1, kv2, b_idx, s_idx, p_idx, w, msW1, msb1, msW2, msb2,
        el, rf, cf, cnt, cnt + NROW);

    scan_kernel<<<2, 1024, 0, stream>>>(cnt, offs, cur);

    scatter_kernel<<<EE / 256, 256, 0, stream>>>(
        rf, cf, cur, cur + NROW, list_row, list_col);

    // row combine: values = v2 (kv2 second half), indexed by col id
    combine_kernel<<<NROW, 128, 0, stream>>>(list_row, offs, el, cf, kv2 + 128, row_heads);
    // col combine: values = v1 (qv1 second half), indexed by row id
    combine_kernel<<<NCOL, 128, 0, stream>>>(list_col, offs + (NROW + 1), el, rf, qv1 + 128, col_heads);

    gemm16_kernel<128><<<NROW / 16, 128, 0, stream>>>(row_heads, Wo1, out);
    gemm16_kernel<128><<<NCOL / 16, 128, 0, stream>>>(col_heads, Wo2, out + (size_t)NROW * 128);
}

// Round 2
// 395.899 us; speedup vs baseline: 1.3020x; 1.3020x over previous
//
#include <hip/hip_runtime.h>
#include <math.h>

#define BB   16
#define SS   1024
#define PP   1024
#define DD   128
#define HH   8
#define HDD  16
#define MSS  32
#define EE   524288
#define NROW (BB*SS)   /* 16384 */
#define NCOL (BB*PP)   /* 16384 */

// ---------------- projection: qv1 = x1@Wqv1, kv2 = x2@Wkv2 (merged) ---------
// 16 rows per block, N=256 cols. A tile in LDS (broadcast), B coalesced (L2).
__global__ __launch_bounds__(256) void proj_kernel(
        const float* __restrict__ x1, const float* __restrict__ x2,
        const float* __restrict__ Wqv1, const float* __restrict__ Wkv2,
        float* __restrict__ qv1, float* __restrict__ kv2) {
    __shared__ float As[16 * 128];
    int t = threadIdx.x;
    const float* A; const float* Bm; float* C; int mb;
    if (blockIdx.x < NROW / 16) { A = x1; Bm = Wqv1; C = qv1; mb = blockIdx.x; }
    else { A = x2; Bm = Wkv2; C = kv2; mb = blockIdx.x - NROW / 16; }
    const float* Arow = A + (size_t)mb * 16 * 128;
    for (int i = t; i < 16 * 128; i += 256) As[i] = Arow[i];
    __syncthreads();
    float acc[16];
#pragma unroll
    for (int i = 0; i < 16; i++) acc[i] = 0.f;
    for (int k = 0; k < 128; k++) {
        float bk = Bm[k * 256 + t];
#pragma unroll
        for (int i = 0; i < 16; i++) acc[i] = fmaf(As[i * 128 + k], bk, acc[i]);
    }
    float* Crow = C + (size_t)mb * 16 * 256 + t;
#pragma unroll
    for (int i = 0; i < 16; i++) Crow[(size_t)i * 256] = acc[i];
}

// ---------------- output: h1 = row_heads@Wo1, h2 = col_heads@Wo2 (merged) ---
__global__ __launch_bounds__(128) void outp_kernel(
        const float* __restrict__ rh, const float* __restrict__ ch,
        const float* __restrict__ Wo1, const float* __restrict__ Wo2,
        float* __restrict__ out) {
    __shared__ float As[16 * 128];
    int t = threadIdx.x;
    const float* A; const float* Bm; float* C; int mb;
    if (blockIdx.x < NROW / 16) { A = rh; Bm = Wo1; C = out; mb = blockIdx.x; }
    else { A = ch; Bm = Wo2; C = out + (size_t)NROW * 128; mb = blockIdx.x - NROW / 16; }
    const float* Arow = A + (size_t)mb * 16 * 128;
    for (int i = t; i < 16 * 128; i += 128) As[i] = Arow[i];
    __syncthreads();
    float acc[16];
#pragma unroll
    for (int i = 0; i < 16; i++) acc[i] = 0.f;
    for (int k = 0; k < 128; k++) {
        float bk = Bm[k * 128 + t];
#pragma unroll
        for (int i = 0; i < 16; i++) acc[i] = fmaf(As[i * 128 + k], bk, acc[i]);
    }
    float* Crow = C + (size_t)mb * 16 * 128 + t;
#pragma unroll
    for (int i = 0; i < 16; i++) Crow[(size_t)i * 128] = acc[i];
}

// ---------------- CSR build ------------------------------------------------
__global__ __launch_bounds__(256) void count_kernel(
        const int* __restrict__ b_idx, const int* __restrict__ s_idx,
        const int* __restrict__ p_idx,
        int* __restrict__ cnt_row, int* __restrict__ cnt_col) {
    int e = blockIdx.x * 256 + threadIdx.x;
    int b = b_idx[e];
    atomicAdd(&cnt_row[b * SS + s_idx[e]], 1);
    atomicAdd(&cnt_col[b * PP + p_idx[e]], 1);
}

// Exclusive scan of 16384 counts -> offsets[16385]; seeds cursors.
__global__ __launch_bounds__(1024) void scan_kernel(const int* __restrict__ cnt,
                                                    int* __restrict__ offs,
                                                    int* __restrict__ cur) {
    const int n = NROW;
    const int* c = cnt + (size_t)blockIdx.x * n;
    int* o = offs + (size_t)blockIdx.x * (n + 1);
    int* cu = cur + (size_t)blockIdx.x * n;
    __shared__ int sdata[1024];
    int t = threadIdx.x;
    int base = t * 16;
    int loc[16];
    int run = 0;
#pragma unroll
    for (int i = 0; i < 16; i++) { loc[i] = run; run += c[base + i]; }
    sdata[t] = run;
    __syncthreads();
    for (int st = 1; st < 1024; st <<= 1) {
        int v = (t >= st) ? sdata[t - st] : 0;
        __syncthreads();
        sdata[t] += v;
        __syncthreads();
    }
    int excl = sdata[t] - run;
#pragma unroll
    for (int i = 0; i < 16; i++) {
        int val = excl + loc[i];
        o[base + i] = val;
        cu[base + i] = val;
    }
    if (t == 1023) o[n] = sdata[1023];
}

// list_row entry: {row, col, e, 0}; list_col entry: {row_pos, row}.
__global__ __launch_bounds__(256) void scatter_kernel(
        const int* __restrict__ b_idx, const int* __restrict__ s_idx,
        const int* __restrict__ p_idx,
        int* __restrict__ cur_row, int* __restrict__ cur_col,
        int4* __restrict__ listr, int2* __restrict__ listc) {
    int e = blockIdx.x * 256 + threadIdx.x;
    int b = b_idx[e];
    int row = b * SS + s_idx[e];
    int col = b * PP + p_idx[e];
    int pr = atomicAdd(&cur_row[row], 1);
    listr[pr] = make_int4(row, col, e, 0);
    int pc = atomicAdd(&cur_col[col], 1);
    listc[pc] = make_int2(pr, row);
}

// ---------------- edge pass (row-sorted order) ------------------------------
// Thread (i,h): i = row-list position, h = head. q reads hit L1 (consecutive
// i share a row); el written sequentially in row-list order.
// MLP weights transposed in LDS to [m*8+h] -> conflict-free (8 banks,
// 8-lane broadcasts) instead of the 8-way conflict of [h*64+m].
__global__ __launch_bounds__(256) void edge_kernel(
        const float* __restrict__ qv1, const float* __restrict__ kv2,
        const int4* __restrict__ listr, const float* __restrict__ w,
        const float* __restrict__ msW1, const float* __restrict__ msb1,
        const float* __restrict__ msW2, const float* __restrict__ msb2,
        float* __restrict__ el) {
    __shared__ float sW1a[MSS * 8], sW1b[MSS * 8], sB1[MSS * 8], sW2[MSS * 8], sB2[8];
    int t = threadIdx.x;
    for (int j = t; j < 512; j += 256) {      // msW1[h][i][m] (h*64+i*32+m)
        int h = j >> 6, ii = (j >> 5) & 1, m = j & 31;
        float v = msW1[j];
        if (ii == 0) sW1a[m * 8 + h] = v; else sW1b[m * 8 + h] = v;
    }
    {                                          // msb1[h][m], msW2[h][m]
        int h = t >> 5, m = t & 31;
        sB1[m * 8 + h] = msb1[t];
        sW2[m * 8 + h] = msW2[t];
    }
    if (t < 8) sB2[t] = msb2[t];
    __syncthreads();

    int gid = blockIdx.x * 256 + t;
    int i = gid >> 3;
    int h = gid & 7;
    int4 en = listr[i];
    int row = en.x, col = en.y, e = en.z;

    const float4* qp = (const float4*)(qv1 + (size_t)row * 256 + h * 16);
    const float4* kp = (const float4*)(kv2 + (size_t)col * 256 + h * 16);
    float dot = 0.f;
#pragma unroll
    for (int j = 0; j < 4; j++) {
        float4 a = qp[j], k4 = kp[j];
        dot = fmaf(a.x, k4.x, dot);
        dot = fmaf(a.y, k4.y, dot);
        dot = fmaf(a.z, k4.z, dot);
        dot = fmaf(a.w, k4.w, dot);
    }
    float logit = dot * 0.25f;  // 1/sqrt(HD=16)
    float we = w[e];

    float outv = sB2[h];
#pragma unroll
    for (int m = 0; m < MSS; m++) {
        float hid = fmaf(logit, sW1a[m * 8 + h], fmaf(we, sW1b[m * 8 + h], sB1[m * 8 + h]));
        hid = fmaxf(hid, 0.f);
        outv = fmaf(hid, sW2[m * 8 + h], outv);
    }
    float score = 10.0f * tanhf(outv);  // TANH_CLIP / TEMP
    el[(size_t)i * 8 + h] = expf(score);
}

// ---------------- dual group-softmax combine (merged row+col) --------------
// Block g < NROW: row group (el streams, v2 gathered by col).
// Block g >= NROW: col group (el gathered by row_pos, v1 gathered by row).
__global__ __launch_bounds__(128) void combine_kernel(
        const int4* __restrict__ listr, const int2* __restrict__ listc,
        const int* __restrict__ offs_row, const int* __restrict__ offs_col,
        const float* __restrict__ el,
        const float* __restrict__ qv1, const float* __restrict__ kv2,
        float* __restrict__ row_heads, float* __restrict__ col_heads) {
    int g = blockIdx.x;
    int t = threadIdx.x;  // t = h*16 + hd
    int h = t >> 4;
    float acc = 0.f, den = 0.f;
    if (g < NROW) {
        int s = offs_row[g], e_ = offs_row[g + 1];
#pragma unroll 2
        for (int i = s; i < e_; i++) {
            int col = listr[i].y;
            float ev = el[(size_t)i * 8 + h];
            float v = kv2[(size_t)col * 256 + 128 + t];
            acc = fmaf(ev, v, acc);
            den += ev;
        }
        row_heads[(size_t)g * 128 + t] = acc / (den + 1e-9f);
    } else {
        int gl = g - NROW;
        int s = offs_col[gl], e_ = offs_col[gl + 1];
#pragma unroll 2
        for (int i = s; i < e_; i++) {
            int2 en = listc[i];
            float ev = el[(size_t)en.x * 8 + h];
            float v = qv1[(size_t)en.y * 256 + 128 + t];
            acc = fmaf(ev, v, acc);
            den += ev;
        }
        col_heads[(size_t)gl * 128 + t] = acc / (den + 1e-9f);
    }
}

extern "C" void kernel_launch(void* const* d_in, const int* in_sizes, int n_in,
                              void* d_out, int out_size, void* d_ws, size_t ws_size,
                              hipStream_t stream) {
    const float* x1   = (const float*)d_in[0];
    const float* x2   = (const float*)d_in[1];
    const int* b_idx  = (const int*)d_in[2];
    const int* s_idx  = (const int*)d_in[3];
    const int* p_idx  = (const int*)d_in[4];
    const float* w    = (const float*)d_in[5];
    const float* Wqv1 = (const float*)d_in[6];
    const float* Wkv2 = (const float*)d_in[7];
    const float* Wo1  = (const float*)d_in[8];
    const float* Wo2  = (const float*)d_in[9];
    const float* msW1 = (const float*)d_in[10];
    const float* msb1 = (const float*)d_in[11];
    const float* msW2 = (const float*)d_in[12];
    const float* msb2 = (const float*)d_in[13];
    float* out = (float*)d_out;

    // Workspace layout (~76.5 MiB).
    float* qv1 = (float*)d_ws;                        // 16384*256
    float* kv2 = qv1 + (size_t)NROW * 256;            // 16384*256
    float* el  = kv2 + (size_t)NCOL * 256;            // E*8 (row-list order)
    float* row_heads = el + (size_t)EE * 8;           // 16384*128
    float* col_heads = row_heads + (size_t)NROW * 128;
    int* ip = (int*)(col_heads + (size_t)NCOL * 128);
    int4* listr = (int4*)ip;        ip += 4 * EE;     // {row,col,e,0}
    int2* listc = (int2*)ip;        ip += 2 * EE;     // {row_pos,row}
    int* cnt = ip;       ip += 2 * NROW;              // cnt_row | cnt_col
    int* offs = ip;      ip += 2 * (NROW + 1);        // offs_row | offs_col
    int* cur = ip;       ip += 2 * NROW;              // cur_row | cur_col

    hipMemsetAsync(cnt, 0, 2 * NROW * sizeof(int), stream);

    proj_kernel<<<2 * (NROW / 16), 256, 0, stream>>>(x1, x2, Wqv1, Wkv2, qv1, kv2);

    count_kernel<<<EE / 256, 256, 0, stream>>>(b_idx, s_idx, p_idx, cnt, cnt + NROW);
    scan_kernel<<<2, 1024, 0, stream>>>(cnt, offs, cur);
    scatter_kernel<<<EE / 256, 256, 0, stream>>>(b_idx, s_idx, p_idx,
                                                 cur, cur + NROW, listr, listc);

    edge_kernel<<<(EE * 8) / 256, 256, 0, stream>>>(
        qv1, kv2, listr, w, msW1, msb1, msW2, msb2, el);

    combine_kernel<<<2 * NROW, 128, 0, stream>>>(
        listr, listc, offs, offs + (NROW + 1), el, qv1, kv2, row_heads, col_heads);

    outp_kernel<<<2 * (NROW / 16), 128, 0, stream>>>(row_heads, col_heads, Wo1, Wo2, out);
}

// Round 3
// 367.724 us; speedup vs baseline: 1.4018x; 1.0766x over previous
//
#include <hip/hip_runtime.h>
#include <math.h>

#define BB   16
#define SS   1024
#define PP   1024
#define HH   8
#define MSS  32
#define EE   524288
#define NROW (BB*SS)   /* 16384 */
#define NCOL (BB*PP)   /* 16384 */
#define ESTRIDE 9      /* floats per edge entry: [0]=other id (bitcast int), [1..8]=ev[h] */

// ---------------- projection: qv1 = x1@Wqv1, kv2 = x2@Wkv2 (merged) ---------
__global__ __launch_bounds__(256) void proj_kernel(
        const float* __restrict__ x1, const float* __restrict__ x2,
        const float* __restrict__ Wqv1, const float* __restrict__ Wkv2,
        float* __restrict__ qv1, float* __restrict__ kv2) {
    __shared__ float As[16 * 128];
    int t = threadIdx.x;
    const float* A; const float* Bm; float* C; int mb;
    if (blockIdx.x < NROW / 16) { A = x1; Bm = Wqv1; C = qv1; mb = blockIdx.x; }
    else { A = x2; Bm = Wkv2; C = kv2; mb = blockIdx.x - NROW / 16; }
    const float* Arow = A + (size_t)mb * 16 * 128;
    for (int i = t; i < 16 * 128; i += 256) As[i] = Arow[i];
    __syncthreads();
    float acc[16];
#pragma unroll
    for (int i = 0; i < 16; i++) acc[i] = 0.f;
    for (int k = 0; k < 128; k++) {
        float bk = Bm[k * 256 + t];
#pragma unroll
        for (int i = 0; i < 16; i++) acc[i] = fmaf(As[i * 128 + k], bk, acc[i]);
    }
    float* Crow = C + (size_t)mb * 16 * 256 + t;
#pragma unroll
    for (int i = 0; i < 16; i++) Crow[(size_t)i * 256] = acc[i];
}

// ---------------- output: h1 = row_heads@Wo1, h2 = col_heads@Wo2 (merged) ---
__global__ __launch_bounds__(128) void outp_kernel(
        const float* __restrict__ rh, const float* __restrict__ ch,
        const float* __restrict__ Wo1, const float* __restrict__ Wo2,
        float* __restrict__ out) {
    __shared__ float As[16 * 128];
    int t = threadIdx.x;
    const float* A; const float* Bm; float* C; int mb;
    if (blockIdx.x < NROW / 16) { A = rh; Bm = Wo1; C = out; mb = blockIdx.x; }
    else { A = ch; Bm = Wo2; C = out + (size_t)NROW * 128; mb = blockIdx.x - NROW / 16; }
    const float* Arow = A + (size_t)mb * 16 * 128;
    for (int i = t; i < 16 * 128; i += 128) As[i] = Arow[i];
    __syncthreads();
    float acc[16];
#pragma unroll
    for (int i = 0; i < 16; i++) acc[i] = 0.f;
    for (int k = 0; k < 128; k++) {
        float bk = Bm[k * 128 + t];
#pragma unroll
        for (int i = 0; i < 16; i++) acc[i] = fmaf(As[i * 128 + k], bk, acc[i]);
    }
    float* Crow = C + (size_t)mb * 16 * 128 + t;
#pragma unroll
    for (int i = 0; i < 16; i++) Crow[(size_t)i * 128] = acc[i];
}

// ---------------- CSR histogram + scan -------------------------------------
__global__ __launch_bounds__(256) void count_kernel(
        const int* __restrict__ b_idx, const int* __restrict__ s_idx,
        const int* __restrict__ p_idx,
        int* __restrict__ cnt_row, int* __restrict__ cnt_col) {
    int e = blockIdx.x * 256 + threadIdx.x;
    int b = b_idx[e];
    atomicAdd(&cnt_row[b * SS + s_idx[e]], 1);
    atomicAdd(&cnt_col[b * PP + p_idx[e]], 1);
}

__global__ __launch_bounds__(1024) void scan_kernel(const int* __restrict__ cnt,
                                                    int* __restrict__ offs,
                                                    int* __restrict__ cur) {
    const int n = NROW;
    const int* c = cnt + (size_t)blockIdx.x * n;
    int* o = offs + (size_t)blockIdx.x * (n + 1);
    int* cu = cur + (size_t)blockIdx.x * n;
    __shared__ int sdata[1024];
    int t = threadIdx.x;
    int base = t * 16;
    int loc[16];
    int run = 0;
#pragma unroll
    for (int i = 0; i < 16; i++) { loc[i] = run; run += c[base + i]; }
    sdata[t] = run;
    __syncthreads();
    for (int st = 1; st < 1024; st <<= 1) {
        int v = (t >= st) ? sdata[t - st] : 0;
        __syncthreads();
        sdata[t] += v;
        __syncthreads();
    }
    int excl = sdata[t] - run;
#pragma unroll
    for (int i = 0; i < 16; i++) {
        int val = excl + loc[i];
        o[base + i] = val;
        cu[base + i] = val;
    }
    if (t == 1023) o[n] = sdata[1023];
}

// ---------------- fused edge + scatter (e-order) ----------------------------
// 8 threads per edge (one per head): q·k dot, score MLP, exp -> ev.
// h==0 grabs cursor positions (2 atomics), broadcast via shfl width-8; the 8
// threads write the packed entry {other, ev[0..7]} to the sorted position for
// BOTH the row list and the col list. Entry is 36B -> 1-2 line touches/side.
// MLP weights in LDS transposed to [m*8+h]: 8 banks x 8-lane broadcast,
// conflict-free (verified SQ_LDS_BANK_CONFLICT==0 in round 2).
__global__ __launch_bounds__(256) void edge_kernel(
        const float* __restrict__ qv1, const float* __restrict__ kv2,
        const int* __restrict__ b_idx, const int* __restrict__ s_idx,
        const int* __restrict__ p_idx, const float* __restrict__ w,
        const float* __restrict__ msW1, const float* __restrict__ msb1,
        const float* __restrict__ msW2, const float* __restrict__ msb2,
        int* __restrict__ cur_row, int* __restrict__ cur_col,
        float* __restrict__ entr, float* __restrict__ entc) {
    __shared__ float sW1a[MSS * 8], sW1b[MSS * 8], sB1[MSS * 8], sW2[MSS * 8], sB2[8];
    int t = threadIdx.x;
    for (int j = t; j < 512; j += 256) {      // msW1[h][i][m]
        int h = j >> 6, ii = (j >> 5) & 1, m = j & 31;
        float v = msW1[j];
        if (ii == 0) sW1a[m * 8 + h] = v; else sW1b[m * 8 + h] = v;
    }
    {
        int h = t >> 5, m = t & 31;
        sB1[m * 8 + h] = msb1[t];
        sW2[m * 8 + h] = msW2[t];
    }
    if (t < 8) sB2[t] = msb2[t];
    __syncthreads();

    int gid = blockIdx.x * 256 + t;
    int e = gid >> 3;
    int h = gid & 7;
    int b = b_idx[e];
    int row = b * SS + s_idx[e];
    int col = b * PP + p_idx[e];

    const float4* qp = (const float4*)(qv1 + (size_t)row * 256 + h * 16);
    const float4* kp = (const float4*)(kv2 + (size_t)col * 256 + h * 16);
    float dot = 0.f;
#pragma unroll
    for (int j = 0; j < 4; j++) {
        float4 a = qp[j], k4 = kp[j];
        dot = fmaf(a.x, k4.x, dot);
        dot = fmaf(a.y, k4.y, dot);
        dot = fmaf(a.z, k4.z, dot);
        dot = fmaf(a.w, k4.w, dot);
    }
    float logit = dot * 0.25f;  // 1/sqrt(HD=16)
    float we = w[e];

    float outv = sB2[h];
#pragma unroll
    for (int m = 0; m < MSS; m++) {
        float hid = fmaf(logit, sW1a[m * 8 + h], fmaf(we, sW1b[m * 8 + h], sB1[m * 8 + h]));
        hid = fmaxf(hid, 0.f);
        outv = fmaf(hid, sW2[m * 8 + h], outv);
    }
    float ev = expf(10.0f * tanhf(outv));  // TANH_CLIP/TEMP, then exp for softmax

    int pr = 0, pc = 0;
    if (h == 0) {
        pr = atomicAdd(&cur_row[row], 1);
        pc = atomicAdd(&cur_col[col], 1);
    }
    pr = __shfl(pr, 0, 8);
    pc = __shfl(pc, 0, 8);

    float* er = entr + (size_t)pr * ESTRIDE;
    float* ec = entc + (size_t)pc * ESTRIDE;
    er[1 + h] = ev;
    ec[1 + h] = ev;
    if (h == 0) {
        er[0] = __int_as_float(col);
        ec[0] = __int_as_float(row);
    }
}

// ---------------- dual group-softmax combine (merged row+col) --------------
// Block g < NROW: row group (entries coalesced, v2 gathered by col).
// Block g >= NROW: col group (entries coalesced, v1 gathered by row).
__global__ __launch_bounds__(128) void combine_kernel(
        const float* __restrict__ entr, const float* __restrict__ entc,
        const int* __restrict__ offs_row, const int* __restrict__ offs_col,
        const float* __restrict__ qv1, const float* __restrict__ kv2,
        float* __restrict__ row_heads, float* __restrict__ col_heads) {
    int g = blockIdx.x;
    int t = threadIdx.x;  // t = h*16 + hd
    int h1 = 1 + (t >> 4);
    const float* ent; const float* vals; const int* offs; float* outp; int gl;
    if (g < NROW) { ent = entr; vals = kv2; offs = offs_row; outp = row_heads; gl = g; }
    else { ent = entc; vals = qv1; offs = offs_col; outp = col_heads; gl = g - NROW; }
    int s = offs[gl], e_ = offs[gl + 1];
    float acc = 0.f, den = 0.f;
#pragma unroll 4
    for (int i = s; i < e_; i++) {
        const float* en = ent + (size_t)i * ESTRIDE;
        int other = __float_as_int(en[0]);
        float ev = en[h1];
        float v = vals[(size_t)other * 256 + 128 + t];
        acc = fmaf(ev, v, acc);
        den += ev;
    }
    outp[(size_t)gl * 128 + t] = acc / (den + 1e-9f);
}

extern "C" void kernel_launch(void* const* d_in, const int* in_sizes, int n_in,
                              void* d_out, int out_size, void* d_ws, size_t ws_size,
                              hipStream_t stream) {
    const float* x1   = (const float*)d_in[0];
    const float* x2   = (const float*)d_in[1];
    const int* b_idx  = (const int*)d_in[2];
    const int* s_idx  = (const int*)d_in[3];
    const int* p_idx  = (const int*)d_in[4];
    const float* w    = (const float*)d_in[5];
    const float* Wqv1 = (const float*)d_in[6];
    const float* Wkv2 = (const float*)d_in[7];
    const float* Wo1  = (const float*)d_in[8];
    const float* Wo2  = (const float*)d_in[9];
    const float* msW1 = (const float*)d_in[10];
    const float* msb1 = (const float*)d_in[11];
    const float* msW2 = (const float*)d_in[12];
    const float* msb2 = (const float*)d_in[13];
    float* out = (float*)d_out;

    // Workspace layout (~86 MiB).
    float* qv1 = (float*)d_ws;                        // 16384*256
    float* kv2 = qv1 + (size_t)NROW * 256;            // 16384*256
    float* entr = kv2 + (size_t)NCOL * 256;           // E*9 (row-sorted entries)
    float* entc = entr + (size_t)EE * ESTRIDE;        // E*9 (col-sorted entries)
    float* row_heads = entc + (size_t)EE * ESTRIDE;   // 16384*128
    float* col_heads = row_heads + (size_t)NROW * 128;
    int* ip = (int*)(col_heads + (size_t)NCOL * 128);
    int* cnt = ip;       ip += 2 * NROW;              // cnt_row | cnt_col
    int* offs = ip;      ip += 2 * (NROW + 1);        // offs_row | offs_col
    int* cur = ip;       ip += 2 * NROW;              // cur_row | cur_col

    hipMemsetAsync(cnt, 0, 2 * NROW * sizeof(int), stream);

    count_kernel<<<EE / 256, 256, 0, stream>>>(b_idx, s_idx, p_idx, cnt, cnt + NROW);
    scan_kernel<<<2, 1024, 0, stream>>>(cnt, offs, cur);

    proj_kernel<<<2 * (NROW / 16), 256, 0, stream>>>(x1, x2, Wqv1, Wkv2, qv1, kv2);

    edge_kernel<<<(EE * 8) / 256, 256, 0, stream>>>(
        qv1, kv2, b_idx, s_idx, p_idx, w, msW1, msb1, msW2, msb2,
        cur, cur + NROW, entr, entc);

    combine_kernel<<<2 * NROW, 128, 0, stream>>>(
        entr, entc, offs, offs + (NROW + 1), qv1, kv2, row_heads, col_heads);

    outp_kernel<<<2 * (NROW / 16), 128, 0, stream>>>(row_heads, col_heads, Wo1, Wo2, out);
}

// Round 4
// 347.150 us; speedup vs baseline: 1.4849x; 1.0593x over previous
//
#include <hip/hip_runtime.h>
#include <hip/hip_fp16.h>
#include <math.h>

#define BB   16
#define SS   1024
#define PP   1024
#define HH   8
#define MSS  32
#define EE   524288
#define NROW (BB*SS)   /* 16384 */
#define NCOL (BB*PP)   /* 16384 */
#define ESTRIDE 9      /* floats per edge entry: [0]=other id (bitcast int), [1..8]=ev[h] */

// ---------------- projection + fused edge-count histogram -------------------
// qf/kf: fp32 [row][128] (q and k halves, compact -> 16 MB gather set for edge)
// v1h/v2h: fp16 [row][128] (v halves -> halves combine's gather bytes)
// Each of the E=2048*256 threads also bumps the row/col histograms (latency
// hidden under the GEMM's FMA stream).
__global__ __launch_bounds__(256) void proj_kernel(
        const float* __restrict__ x1, const float* __restrict__ x2,
        const float* __restrict__ Wqv1, const float* __restrict__ Wkv2,
        const int* __restrict__ b_idx, const int* __restrict__ s_idx,
        const int* __restrict__ p_idx,
        float* __restrict__ qf, float* __restrict__ kf,
        __half* __restrict__ v1h, __half* __restrict__ v2h,
        int* __restrict__ cnt_row, int* __restrict__ cnt_col) {
    __shared__ float As[16 * 128];
    int t = threadIdx.x;

    // fused histogram (one edge per thread; grid == E exactly)
    {
        int e = blockIdx.x * 256 + t;
        int b = b_idx[e];
        atomicAdd(&cnt_row[b * SS + s_idx[e]], 1);
        atomicAdd(&cnt_col[b * PP + p_idx[e]], 1);
    }

    const float* A; const float* Bm; float* Cq; __half* Cv; int mb;
    if (blockIdx.x < NROW / 16) { A = x1; Bm = Wqv1; Cq = qf; Cv = v1h; mb = blockIdx.x; }
    else { A = x2; Bm = Wkv2; Cq = kf; Cv = v2h; mb = blockIdx.x - NROW / 16; }
    const float* Arow = A + (size_t)mb * 16 * 128;
    for (int i = t; i < 16 * 128; i += 256) As[i] = Arow[i];
    __syncthreads();
    float acc[16];
#pragma unroll
    for (int i = 0; i < 16; i++) acc[i] = 0.f;
    for (int k = 0; k < 128; k++) {
        float bk = Bm[k * 256 + t];
#pragma unroll
        for (int i = 0; i < 16; i++) acc[i] = fmaf(As[i * 128 + k], bk, acc[i]);
    }
    if (t < 128) {       // q/k half (cols 0..127), fp32
        float* Crow = Cq + (size_t)mb * 16 * 128 + t;
#pragma unroll
        for (int i = 0; i < 16; i++) Crow[(size_t)i * 128] = acc[i];
    } else {             // v half (cols 128..255), fp16
        __half* Crow = Cv + (size_t)mb * 16 * 128 + (t - 128);
#pragma unroll
        for (int i = 0; i < 16; i++) Crow[(size_t)i * 128] = __float2half(acc[i]);
    }
}

// ---------------- output: h1 = row_heads@Wo1, h2 = col_heads@Wo2 (merged) ---
__global__ __launch_bounds__(128) void outp_kernel(
        const float* __restrict__ rh, const float* __restrict__ ch,
        const float* __restrict__ Wo1, const float* __restrict__ Wo2,
        float* __restrict__ out) {
    __shared__ float As[16 * 128];
    int t = threadIdx.x;
    const float* A; const float* Bm; float* C; int mb;
    if (blockIdx.x < NROW / 16) { A = rh; Bm = Wo1; C = out; mb = blockIdx.x; }
    else { A = ch; Bm = Wo2; C = out + (size_t)NROW * 128; mb = blockIdx.x - NROW / 16; }
    const float* Arow = A + (size_t)mb * 16 * 128;
    for (int i = t; i < 16 * 128; i += 128) As[i] = Arow[i];
    __syncthreads();
    float acc[16];
#pragma unroll
    for (int i = 0; i < 16; i++) acc[i] = 0.f;
    for (int k = 0; k < 128; k++) {
        float bk = Bm[k * 128 + t];
#pragma unroll
        for (int i = 0; i < 16; i++) acc[i] = fmaf(As[i * 128 + k], bk, acc[i]);
    }
    float* Crow = C + (size_t)mb * 16 * 128 + t;
#pragma unroll
    for (int i = 0; i < 16; i++) Crow[(size_t)i * 128] = acc[i];
}

// ---------------- scan: counts -> offsets[16385] + cursor seed --------------
__global__ __launch_bounds__(1024) void scan_kernel(const int* __restrict__ cnt,
                                                    int* __restrict__ offs,
                                                    int* __restrict__ cur) {
    const int n = NROW;
    const int* c = cnt + (size_t)blockIdx.x * n;
    int* o = offs + (size_t)blockIdx.x * (n + 1);
    int* cu = cur + (size_t)blockIdx.x * n;
    __shared__ int sdata[1024];
    int t = threadIdx.x;
    int base = t * 16;
    int loc[16];
    int run = 0;
#pragma unroll
    for (int i = 0; i < 16; i++) { loc[i] = run; run += c[base + i]; }
    sdata[t] = run;
    __syncthreads();
    for (int st = 1; st < 1024; st <<= 1) {
        int v = (t >= st) ? sdata[t - st] : 0;
        __syncthreads();
        sdata[t] += v;
        __syncthreads();
    }
    int excl = sdata[t] - run;
#pragma unroll
    for (int i = 0; i < 16; i++) {
        int val = excl + loc[i];
        o[base + i] = val;
        cu[base + i] = val;
    }
    if (t == 1023) o[n] = sdata[1023];
}

// ---------------- fused edge + scatter (e-order) ----------------------------
// 8 threads per edge (one per head): q·k dot, score MLP, exp -> ev.
// h==0 grabs cursor positions (2 atomics), broadcast via shfl width-8; the 8
// threads write the packed entry {other, ev[0..7]} to the sorted position for
// BOTH the row list and the col list.
// MLP weights in LDS transposed to [m*8+h]: conflict-free broadcast.
__global__ __launch_bounds__(256) void edge_kernel(
        const float* __restrict__ qf, const float* __restrict__ kf,
        const int* __restrict__ b_idx, const int* __restrict__ s_idx,
        const int* __restrict__ p_idx, const float* __restrict__ w,
        const float* __restrict__ msW1, const float* __restrict__ msb1,
        const float* __restrict__ msW2, const float* __restrict__ msb2,
        int* __restrict__ cur_row, int* __restrict__ cur_col,
        float* __restrict__ entr, float* __restrict__ entc) {
    __shared__ float sW1a[MSS * 8], sW1b[MSS * 8], sB1[MSS * 8], sW2[MSS * 8], sB2[8];
    int t = threadIdx.x;
    for (int j = t; j < 512; j += 256) {      // msW1[h][i][m]
        int h = j >> 6, ii = (j >> 5) & 1, m = j & 31;
        float v = msW1[j];
        if (ii == 0) sW1a[m * 8 + h] = v; else sW1b[m * 8 + h] = v;
    }
    {
        int h = t >> 5, m = t & 31;
        sB1[m * 8 + h] = msb1[t];
        sW2[m * 8 + h] = msW2[t];
    }
    if (t < 8) sB2[t] = msb2[t];
    __syncthreads();

    int gid = blockIdx.x * 256 + t;
    int e = gid >> 3;
    int h = gid & 7;
    int b = b_idx[e];
    int row = b * SS + s_idx[e];
    int col = b * PP + p_idx[e];

    const float4* qp = (const float4*)(qf + (size_t)row * 128 + h * 16);
    const float4* kp = (const float4*)(kf + (size_t)col * 128 + h * 16);
    float dot = 0.f;
#pragma unroll
    for (int j = 0; j < 4; j++) {
        float4 a = qp[j], k4 = kp[j];
        dot = fmaf(a.x, k4.x, dot);
        dot = fmaf(a.y, k4.y, dot);
        dot = fmaf(a.z, k4.z, dot);
        dot = fmaf(a.w, k4.w, dot);
    }
    float logit = dot * 0.25f;  // 1/sqrt(HD=16)
    float we = w[e];

    float outv = sB2[h];
#pragma unroll
    for (int m = 0; m < MSS; m++) {
        float hid = fmaf(logit, sW1a[m * 8 + h], fmaf(we, sW1b[m * 8 + h], sB1[m * 8 + h]));
        hid = fmaxf(hid, 0.f);
        outv = fmaf(hid, sW2[m * 8 + h], outv);
    }
    float ev = expf(10.0f * tanhf(outv));  // TANH_CLIP/TEMP, then exp for softmax

    int pr = 0, pc = 0;
    if (h == 0) {
        pr = atomicAdd(&cur_row[row], 1);
        pc = atomicAdd(&cur_col[col], 1);
    }
    pr = __shfl(pr, 0, 8);
    pc = __shfl(pc, 0, 8);

    float* er = entr + (size_t)pr * ESTRIDE;
    float* ec = entc + (size_t)pc * ESTRIDE;
    er[1 + h] = ev;
    ec[1 + h] = ev;
    if (h == 0) {
        er[0] = __int_as_float(col);
        ec[0] = __int_as_float(row);
    }
}

// ---------------- dual group-softmax combine (merged row+col) --------------
// Block g < NROW: row group (entries coalesced, v2 fp16 gathered by col).
// Block g >= NROW: col group (entries coalesced, v1 fp16 gathered by row).
__global__ __launch_bounds__(128) void combine_kernel(
        const float* __restrict__ entr, const float* __restrict__ entc,
        const int* __restrict__ offs_row, const int* __restrict__ offs_col,
        const __half* __restrict__ v1h, const __half* __restrict__ v2h,
        float* __restrict__ row_heads, float* __restrict__ col_heads) {
    int g = blockIdx.x;
    int t = threadIdx.x;  // t = h*16 + hd
    int h1 = 1 + (t >> 4);
    const float* ent; const __half* vals; const int* offs; float* outp; int gl;
    if (g < NROW) { ent = entr; vals = v2h; offs = offs_row; outp = row_heads; gl = g; }
    else { ent = entc; vals = v1h; offs = offs_col; outp = col_heads; gl = g - NROW; }
    int s = offs[gl], e_ = offs[gl + 1];
    float acc = 0.f, den = 0.f;
#pragma unroll 4
    for (int i = s; i < e_; i++) {
        const float* en = ent + (size_t)i * ESTRIDE;
        int other = __float_as_int(en[0]);
        float ev = en[h1];
        float v = __half2float(vals[(size_t)other * 128 + t]);
        acc = fmaf(ev, v, acc);
        den += ev;
    }
    outp[(size_t)gl * 128 + t] = acc / (den + 1e-9f);
}

extern "C" void kernel_launch(void* const* d_in, const int* in_sizes, int n_in,
                              void* d_out, int out_size, void* d_ws, size_t ws_size,
                              hipStream_t stream) {
    const float* x1   = (const float*)d_in[0];
    const float* x2   = (const float*)d_in[1];
    const int* b_idx  = (const int*)d_in[2];
    const int* s_idx  = (const int*)d_in[3];
    const int* p_idx  = (const int*)d_in[4];
    const float* w    = (const float*)d_in[5];
    const float* Wqv1 = (const float*)d_in[6];
    const float* Wkv2 = (const float*)d_in[7];
    const float* Wo1  = (const float*)d_in[8];
    const float* Wo2  = (const float*)d_in[9];
    const float* msW1 = (const float*)d_in[10];
    const float* msb1 = (const float*)d_in[11];
    const float* msW2 = (const float*)d_in[12];
    const float* msb2 = (const float*)d_in[13];
    float* out = (float*)d_out;

    // Workspace layout (~78 MiB).
    float* qf = (float*)d_ws;                         // 16384*128 f32 (8 MB)
    float* kf = qf + (size_t)NROW * 128;              // 16384*128 f32 (8 MB)
    __half* v1h = (__half*)(kf + (size_t)NCOL * 128); // 16384*128 f16 (4 MB)
    __half* v2h = v1h + (size_t)NROW * 128;           // 16384*128 f16 (4 MB)
    float* entr = (float*)(v2h + (size_t)NCOL * 128); // E*9 f32 (18.9 MB)
    float* entc = entr + (size_t)EE * ESTRIDE;        // E*9 f32 (18.9 MB)
    float* row_heads = entc + (size_t)EE * ESTRIDE;   // 16384*128 (8 MB)
    float* col_heads = row_heads + (size_t)NROW * 128;// (8 MB)
    int* ip = (int*)(col_heads + (size_t)NCOL * 128);
    int* cnt = ip;       ip += 2 * NROW;              // cnt_row | cnt_col
    int* offs = ip;      ip += 2 * (NROW + 1);        // offs_row | offs_col
    int* cur = ip;       ip += 2 * NROW;              // cur_row | cur_col

    hipMemsetAsync(cnt, 0, 2 * NROW * sizeof(int), stream);

    proj_kernel<<<2 * (NROW / 16), 256, 0, stream>>>(
        x1, x2, Wqv1, Wkv2, b_idx, s_idx, p_idx,
        qf, kf, v1h, v2h, cnt, cnt + NROW);

    scan_kernel<<<2, 1024, 0, stream>>>(cnt, offs, cur);

    edge_kernel<<<(EE * 8) / 256, 256, 0, stream>>>(
        qf, kf, b_idx, s_idx, p_idx, w, msW1, msb1, msW2, msb2,
        cur, cur + NROW, entr, entc);

    combine_kernel<<<2 * NROW, 128, 0, stream>>>(
        entr, entc, offs, offs + (NROW + 1), v1h, v2h, row_heads, col_heads);

    outp_kernel<<<2 * (NROW / 16), 128, 0, stream>>>(row_heads, col_heads, Wo1, Wo2, out);
}

// Round 5
// 335.905 us; speedup vs baseline: 1.5346x; 1.0335x over previous
//
#include <hip/hip_runtime.h>
#include <hip/hip_fp16.h>
#include <math.h>

#define BB   16
#define SS   1024
#define PP   1024
#define HH   8
#define MSS  32
#define EE   524288
#define NROW (BB*SS)   /* 16384 */
#define NCOL (BB*PP)   /* 16384 */
#define ESTRIDE 5      /* dwords per edge entry: [0]=other id, [1..4]=8 x fp16 ev */

// ---------------- projection + fused edge-count histogram -------------------
// qf/kf: fp32 [row][128]; v1h/v2h: fp16 [row][128].
__global__ __launch_bounds__(256) void proj_kernel(
        const float* __restrict__ x1, const float* __restrict__ x2,
        const float* __restrict__ Wqv1, const float* __restrict__ Wkv2,
        const int* __restrict__ b_idx, const int* __restrict__ s_idx,
        const int* __restrict__ p_idx,
        float* __restrict__ qf, float* __restrict__ kf,
        __half* __restrict__ v1h, __half* __restrict__ v2h,
        int* __restrict__ cnt_row, int* __restrict__ cnt_col) {
    __shared__ float As[16 * 128];
    int t = threadIdx.x;

    // fused histogram (one edge per thread; grid == E exactly)
    {
        int e = blockIdx.x * 256 + t;
        int b = b_idx[e];
        atomicAdd(&cnt_row[b * SS + s_idx[e]], 1);
        atomicAdd(&cnt_col[b * PP + p_idx[e]], 1);
    }

    const float* A; const float* Bm; float* Cq; __half* Cv; int mb;
    if (blockIdx.x < NROW / 16) { A = x1; Bm = Wqv1; Cq = qf; Cv = v1h; mb = blockIdx.x; }
    else { A = x2; Bm = Wkv2; Cq = kf; Cv = v2h; mb = blockIdx.x - NROW / 16; }
    const float* Arow = A + (size_t)mb * 16 * 128;
    for (int i = t; i < 16 * 128; i += 256) As[i] = Arow[i];
    __syncthreads();
    float acc[16];
#pragma unroll
    for (int i = 0; i < 16; i++) acc[i] = 0.f;
    for (int k = 0; k < 128; k++) {
        float bk = Bm[k * 256 + t];
#pragma unroll
        for (int i = 0; i < 16; i++) acc[i] = fmaf(As[i * 128 + k], bk, acc[i]);
    }
    if (t < 128) {       // q/k half (cols 0..127), fp32
        float* Crow = Cq + (size_t)mb * 16 * 128 + t;
#pragma unroll
        for (int i = 0; i < 16; i++) Crow[(size_t)i * 128] = acc[i];
    } else {             // v half (cols 128..255), fp16
        __half* Crow = Cv + (size_t)mb * 16 * 128 + (t - 128);
#pragma unroll
        for (int i = 0; i < 16; i++) Crow[(size_t)i * 128] = __float2half(acc[i]);
    }
}

// ---------------- output: h1 = row_heads@Wo1, h2 = col_heads@Wo2 (merged) ---
__global__ __launch_bounds__(128) void outp_kernel(
        const float* __restrict__ rh, const float* __restrict__ ch,
        const float* __restrict__ Wo1, const float* __restrict__ Wo2,
        float* __restrict__ out) {
    __shared__ float As[16 * 128];
    int t = threadIdx.x;
    const float* A; const float* Bm; float* C; int mb;
    if (blockIdx.x < NROW / 16) { A = rh; Bm = Wo1; C = out; mb = blockIdx.x; }
    else { A = ch; Bm = Wo2; C = out + (size_t)NROW * 128; mb = blockIdx.x - NROW / 16; }
    const float* Arow = A + (size_t)mb * 16 * 128;
    for (int i = t; i < 16 * 128; i += 128) As[i] = Arow[i];
    __syncthreads();
    float acc[16];
#pragma unroll
    for (int i = 0; i < 16; i++) acc[i] = 0.f;
    for (int k = 0; k < 128; k++) {
        float bk = Bm[k * 128 + t];
#pragma unroll
        for (int i = 0; i < 16; i++) acc[i] = fmaf(As[i * 128 + k], bk, acc[i]);
    }
    float* Crow = C + (size_t)mb * 16 * 128 + t;
#pragma unroll
    for (int i = 0; i < 16; i++) Crow[(size_t)i * 128] = acc[i];
}

// ---------------- scan: counts -> offsets[16385] + cursor seed --------------
__global__ __launch_bounds__(1024) void scan_kernel(const int* __restrict__ cnt,
                                                    int* __restrict__ offs,
                                                    int* __restrict__ cur) {
    const int n = NROW;
    const int* c = cnt + (size_t)blockIdx.x * n;
    int* o = offs + (size_t)blockIdx.x * (n + 1);
    int* cu = cur + (size_t)blockIdx.x * n;
    __shared__ int sdata[1024];
    int t = threadIdx.x;
    int base = t * 16;
    int loc[16];
    int run = 0;
#pragma unroll
    for (int i = 0; i < 16; i++) { loc[i] = run; run += c[base + i]; }
    sdata[t] = run;
    __syncthreads();
    for (int st = 1; st < 1024; st <<= 1) {
        int v = (t >= st) ? sdata[t - st] : 0;
        __syncthreads();
        sdata[t] += v;
        __syncthreads();
    }
    int excl = sdata[t] - run;
#pragma unroll
    for (int i = 0; i < 16; i++) {
        int val = excl + loc[i];
        o[base + i] = val;
        cu[base + i] = val;
    }
    if (t == 1023) o[n] = sdata[1023];
}

// ---------------- fused edge + scatter (e-order), coalesced loads -----------
// 8 lanes per edge. Lane l loads float4 chunk (j*8+l) of the q and k rows:
// each load instruction covers 128B CONTIGUOUS per edge (full 64B lines,
// 16 lines/wave/instr instead of 64 partial-line touches). partial[j] holds
// the dot of chunk j*8+l, which belongs to head 2j+(l>>2); summing the 4-lane
// subgroup (shfl_xor 1,2) leaves lane l owning head hh=2*(l&3)+(l>>2) locally
// as p[l&3] -- no redistribution shuffle needed. hh is a permutation of 0..7
// so the [m*8+hh] LDS MLP access stays conflict-free.
__global__ __launch_bounds__(256) void edge_kernel(
        const float* __restrict__ qf, const float* __restrict__ kf,
        const int* __restrict__ b_idx, const int* __restrict__ s_idx,
        const int* __restrict__ p_idx, const float* __restrict__ w,
        const float* __restrict__ msW1, const float* __restrict__ msb1,
        const float* __restrict__ msW2, const float* __restrict__ msb2,
        int* __restrict__ cur_row, int* __restrict__ cur_col,
        float* __restrict__ entr, float* __restrict__ entc) {
    __shared__ float sW1a[MSS * 8], sW1b[MSS * 8], sB1[MSS * 8], sW2[MSS * 8], sB2[8];
    int t = threadIdx.x;
    for (int j = t; j < 512; j += 256) {      // msW1[h][i][m]
        int h = j >> 6, ii = (j >> 5) & 1, m = j & 31;
        float v = msW1[j];
        if (ii == 0) sW1a[m * 8 + h] = v; else sW1b[m * 8 + h] = v;
    }
    {
        int h = t >> 5, m = t & 31;
        sB1[m * 8 + h] = msb1[t];
        sW2[m * 8 + h] = msW2[t];
    }
    if (t < 8) sB2[t] = msb2[t];
    __syncthreads();

    int gid = blockIdx.x * 256 + t;
    int e = gid >> 3;
    int l = gid & 7;
    int b = b_idx[e];
    int row = b * SS + s_idx[e];
    int col = b * PP + p_idx[e];

    const float4* qp4 = (const float4*)(qf + (size_t)row * 128);
    const float4* kp4 = (const float4*)(kf + (size_t)col * 128);
    float p0, p1, p2, p3;
    {
        float4 a = qp4[l],      k4 = kp4[l];
        p0 = fmaf(a.x, k4.x, fmaf(a.y, k4.y, fmaf(a.z, k4.z, a.w * k4.w)));
    }
    {
        float4 a = qp4[8 + l],  k4 = kp4[8 + l];
        p1 = fmaf(a.x, k4.x, fmaf(a.y, k4.y, fmaf(a.z, k4.z, a.w * k4.w)));
    }
    {
        float4 a = qp4[16 + l], k4 = kp4[16 + l];
        p2 = fmaf(a.x, k4.x, fmaf(a.y, k4.y, fmaf(a.z, k4.z, a.w * k4.w)));
    }
    {
        float4 a = qp4[24 + l], k4 = kp4[24 + l];
        p3 = fmaf(a.x, k4.x, fmaf(a.y, k4.y, fmaf(a.z, k4.z, a.w * k4.w)));
    }
    // sum over the 4-lane subgroup (masks 1,2 stay inside the subgroup)
    p0 += __shfl_xor(p0, 1); p0 += __shfl_xor(p0, 2);
    p1 += __shfl_xor(p1, 1); p1 += __shfl_xor(p1, 2);
    p2 += __shfl_xor(p2, 1); p2 += __shfl_xor(p2, 2);
    p3 += __shfl_xor(p3, 1); p3 += __shfl_xor(p3, 2);

    int js = l & 3;
    float dot = js == 0 ? p0 : (js == 1 ? p1 : (js == 2 ? p2 : p3));
    int hh = 2 * js + (l >> 2);   // this lane's head

    float logit = dot * 0.25f;    // 1/sqrt(HD=16)
    float we = w[e];

    float outv = sB2[hh];
#pragma unroll
    for (int m = 0; m < MSS; m++) {
        float hid = fmaf(logit, sW1a[m * 8 + hh], fmaf(we, sW1b[m * 8 + hh], sB1[m * 8 + hh]));
        hid = fmaxf(hid, 0.f);
        outv = fmaf(hid, sW2[m * 8 + hh], outv);
    }
    float ev = expf(10.0f * tanhf(outv));  // TANH_CLIP/TEMP, then exp
    __half evh = __float2half(ev);

    int pr = 0, pc = 0;
    if (l == 0) {
        pr = atomicAdd(&cur_row[row], 1);
        pc = atomicAdd(&cur_col[col], 1);
    }
    pr = __shfl(pr, 0, 8);
    pc = __shfl(pc, 0, 8);

    float* er = entr + (size_t)pr * ESTRIDE;
    float* ec = entc + (size_t)pc * ESTRIDE;
    ((__half*)er)[2 + hh] = evh;
    ((__half*)ec)[2 + hh] = evh;
    if (l == 0) {
        er[0] = __int_as_float(col);
        ec[0] = __int_as_float(row);
    }
}

// ---------------- dual group-softmax combine (merged row+col) --------------
__global__ __launch_bounds__(128) void combine_kernel(
        const float* __restrict__ entr, const float* __restrict__ entc,
        const int* __restrict__ offs_row, const int* __restrict__ offs_col,
        const __half* __restrict__ v1h, const __half* __restrict__ v2h,
        float* __restrict__ row_heads, float* __restrict__ col_heads) {
    int g = blockIdx.x;
    int t = threadIdx.x;  // t = h*16 + hd
    int h = t >> 4;
    const float* ent; const __half* vals; const int* offs; float* outp; int gl;
    if (g < NROW) { ent = entr; vals = v2h; offs = offs_row; outp = row_heads; gl = g; }
    else { ent = entc; vals = v1h; offs = offs_col; outp = col_heads; gl = g - NROW; }
    int s = offs[gl], e_ = offs[gl + 1];
    float acc = 0.f, den = 0.f;
#pragma unroll 4
    for (int i = s; i < e_; i++) {
        const float* en = ent + (size_t)i * ESTRIDE;
        int other = __float_as_int(en[0]);
        float ev = __half2float(((const __half*)en)[2 + h]);
        float v = __half2float(vals[(size_t)other * 128 + t]);
        acc = fmaf(ev, v, acc);
        den += ev;
    }
    outp[(size_t)gl * 128 + t] = acc / (den + 1e-9f);
}

extern "C" void kernel_launch(void* const* d_in, const int* in_sizes, int n_in,
                              void* d_out, int out_size, void* d_ws, size_t ws_size,
                              hipStream_t stream) {
    const float* x1   = (const float*)d_in[0];
    const float* x2   = (const float*)d_in[1];
    const int* b_idx  = (const int*)d_in[2];
    const int* s_idx  = (const int*)d_in[3];
    const int* p_idx  = (const int*)d_in[4];
    const float* w    = (const float*)d_in[5];
    const float* Wqv1 = (const float*)d_in[6];
    const float* Wkv2 = (const float*)d_in[7];
    const float* Wo1  = (const float*)d_in[8];
    const float* Wo2  = (const float*)d_in[9];
    const float* msW1 = (const float*)d_in[10];
    const float* msb1 = (const float*)d_in[11];
    const float* msW2 = (const float*)d_in[12];
    const float* msb2 = (const float*)d_in[13];
    float* out = (float*)d_out;

    // Workspace layout (~62 MiB).
    float* qf = (float*)d_ws;                         // 16384*128 f32 (8 MB)
    float* kf = qf + (size_t)NROW * 128;              // 16384*128 f32 (8 MB)
    __half* v1h = (__half*)(kf + (size_t)NCOL * 128); // 16384*128 f16 (4 MB)
    __half* v2h = v1h + (size_t)NROW * 128;           // 16384*128 f16 (4 MB)
    float* entr = (float*)(v2h + (size_t)NCOL * 128); // E*5 dwords (10.5 MB)
    float* entc = entr + (size_t)EE * ESTRIDE;        // E*5 dwords (10.5 MB)
    float* row_heads = entc + (size_t)EE * ESTRIDE;   // 16384*128 (8 MB)
    float* col_heads = row_heads + (size_t)NROW * 128;// (8 MB)
    int* ip = (int*)(col_heads + (size_t)NCOL * 128);
    int* cnt = ip;       ip += 2 * NROW;              // cnt_row | cnt_col
    int* offs = ip;      ip += 2 * (NROW + 1);        // offs_row | offs_col
    int* cur = ip;       ip += 2 * NROW;              // cur_row | cur_col

    hipMemsetAsync(cnt, 0, 2 * NROW * sizeof(int), stream);

    proj_kernel<<<2 * (NROW / 16), 256, 0, stream>>>(
        x1, x2, Wqv1, Wkv2, b_idx, s_idx, p_idx,
        qf, kf, v1h, v2h, cnt, cnt + NROW);

    scan_kernel<<<2, 1024, 0, stream>>>(cnt, offs, cur);

    edge_kernel<<<(EE * 8) / 256, 256, 0, stream>>>(
        qf, kf, b_idx, s_idx, p_idx, w, msW1, msb1, msW2, msb2,
        cur, cur + NROW, entr, entc);

    combine_kernel<<<2 * NROW, 128, 0, stream>>>(
        entr, entc, offs, offs + (NROW + 1), v1h, v2h, row_heads, col_heads);

    outp_kernel<<<2 * (NROW / 16), 128, 0, stream>>>(row_heads, col_heads, Wo1, Wo2, out);
}

// Round 6
// 321.331 us; speedup vs baseline: 1.6042x; 1.0454x over previous
//
#include <hip/hip_runtime.h>
#include <hip/hip_fp16.h>
#include <math.h>

#define BB   16
#define SS   1024
#define PP   1024
#define HH   8
#define MSS  32
#define EE   524288
#define NROW (BB*SS)   /* 16384 */
#define NCOL (BB*PP)   /* 16384 */
#define ESTRIDE 5      /* dwords per edge entry: [0]=other id, [1..4]=8 x fp16 ev */
#define NBPX 2112      /* edge blocks per XCD slot (32 edges/block; grid-stride covers skew) */

// ---------------- projection + fused edge-count histogram -------------------
// qf/kf: fp32 [row][128]; v1h/v2h: fp16 [row][128].
__global__ __launch_bounds__(256) void proj_kernel(
        const float* __restrict__ x1, const float* __restrict__ x2,
        const float* __restrict__ Wqv1, const float* __restrict__ Wkv2,
        const int* __restrict__ b_idx, const int* __restrict__ s_idx,
        const int* __restrict__ p_idx,
        float* __restrict__ qf, float* __restrict__ kf,
        __half* __restrict__ v1h, __half* __restrict__ v2h,
        int* __restrict__ cnt_row, int* __restrict__ cnt_col) {
    __shared__ float As[16 * 128];
    int t = threadIdx.x;

    // fused histogram (one edge per thread; grid == E exactly)
    {
        int e = blockIdx.x * 256 + t;
        int b = b_idx[e];
        atomicAdd(&cnt_row[b * SS + s_idx[e]], 1);
        atomicAdd(&cnt_col[b * PP + p_idx[e]], 1);
    }

    const float* A; const float* Bm; float* Cq; __half* Cv; int mb;
    if (blockIdx.x < NROW / 16) { A = x1; Bm = Wqv1; Cq = qf; Cv = v1h; mb = blockIdx.x; }
    else { A = x2; Bm = Wkv2; Cq = kf; Cv = v2h; mb = blockIdx.x - NROW / 16; }
    const float* Arow = A + (size_t)mb * 16 * 128;
    for (int i = t; i < 16 * 128; i += 256) As[i] = Arow[i];
    __syncthreads();
    float acc[16];
#pragma unroll
    for (int i = 0; i < 16; i++) acc[i] = 0.f;
    for (int k = 0; k < 128; k++) {
        float bk = Bm[k * 256 + t];
#pragma unroll
        for (int i = 0; i < 16; i++) acc[i] = fmaf(As[i * 128 + k], bk, acc[i]);
    }
    if (t < 128) {       // q/k half (cols 0..127), fp32
        float* Crow = Cq + (size_t)mb * 16 * 128 + t;
#pragma unroll
        for (int i = 0; i < 16; i++) Crow[(size_t)i * 128] = acc[i];
    } else {             // v half (cols 128..255), fp16
        __half* Crow = Cv + (size_t)mb * 16 * 128 + (t - 128);
#pragma unroll
        for (int i = 0; i < 16; i++) Crow[(size_t)i * 128] = __float2half(acc[i]);
    }
}

// ---------------- output: h1 = row_heads@Wo1, h2 = col_heads@Wo2 (merged) ---
__global__ __launch_bounds__(128) void outp_kernel(
        const float* __restrict__ rh, const float* __restrict__ ch,
        const float* __restrict__ Wo1, const float* __restrict__ Wo2,
        float* __restrict__ out) {
    __shared__ float As[16 * 128];
    int t = threadIdx.x;
    const float* A; const float* Bm; float* C; int mb;
    if (blockIdx.x < NROW / 16) { A = rh; Bm = Wo1; C = out; mb = blockIdx.x; }
    else { A = ch; Bm = Wo2; C = out + (size_t)NROW * 128; mb = blockIdx.x - NROW / 16; }
    const float* Arow = A + (size_t)mb * 16 * 128;
    for (int i = t; i < 16 * 128; i += 128) As[i] = Arow[i];
    __syncthreads();
    float acc[16];
#pragma unroll
    for (int i = 0; i < 16; i++) acc[i] = 0.f;
    for (int k = 0; k < 128; k++) {
        float bk = Bm[k * 128 + t];
#pragma unroll
        for (int i = 0; i < 16; i++) acc[i] = fmaf(As[i * 128 + k], bk, acc[i]);
    }
    float* Crow = C + (size_t)mb * 16 * 128 + t;
#pragma unroll
    for (int i = 0; i < 16; i++) Crow[(size_t)i * 128] = acc[i];
}

// ------- scan: counts -> offsets[16385] + cursor seed + batch offsets -------
// boffs[b] for the batch bucketing come free: offs_row[b*1024] = #edges with
// batch < b (row id is batch-major). Rows block (blockIdx 0) seeds bcur.
__global__ __launch_bounds__(1024) void scan_kernel(const int* __restrict__ cnt,
                                                    int* __restrict__ offs,
                                                    int* __restrict__ cur,
                                                    int* __restrict__ bcur) {
    const int n = NROW;
    const int* c = cnt + (size_t)blockIdx.x * n;
    int* o = offs + (size_t)blockIdx.x * (n + 1);
    int* cu = cur + (size_t)blockIdx.x * n;
    __shared__ int sdata[1024];
    int t = threadIdx.x;
    int base = t * 16;
    int loc[16];
    int run = 0;
#pragma unroll
    for (int i = 0; i < 16; i++) { loc[i] = run; run += c[base + i]; }
    sdata[t] = run;
    __syncthreads();
    for (int st = 1; st < 1024; st <<= 1) {
        int v = (t >= st) ? sdata[t - st] : 0;
        __syncthreads();
        sdata[t] += v;
        __syncthreads();
    }
    int excl = sdata[t] - run;
#pragma unroll
    for (int i = 0; i < 16; i++) {
        int idx = base + i;
        int val = excl + loc[i];
        o[idx] = val;
        cu[idx] = val;
        if (blockIdx.x == 0 && (idx & 1023) == 0) bcur[idx >> 10] = val;
    }
    if (t == 1023) o[n] = sdata[1023];
}

// ---------------- batch bucket-sort of edges --------------------------------
// Packs {row, col, w} per edge into ebuf in batch-sorted order. Block-level
// LDS aggregation -> only 16 global atomics per block; per-block positions are
// contiguous chunks per bucket, so writes are dense.
__global__ __launch_bounds__(1024) void bucket_kernel(
        const int* __restrict__ b_idx, const int* __restrict__ s_idx,
        const int* __restrict__ p_idx, const float* __restrict__ w,
        int* __restrict__ bcur, int4* __restrict__ ebuf) {
    __shared__ int lcnt[16], lbase[16];
    int t = threadIdx.x;
    if (t < 16) lcnt[t] = 0;
    __syncthreads();
    int e = blockIdx.x * 1024 + t;
    int b = b_idx[e];
    int row = b * SS + s_idx[e];
    int col = b * PP + p_idx[e];
    float we = w[e];
    int myloc = atomicAdd(&lcnt[b], 1);
    __syncthreads();
    if (t < 16) lbase[t] = atomicAdd(&bcur[t], lcnt[t]);
    __syncthreads();
    ebuf[lbase[b] + myloc] = make_int4(row, col, __float_as_int(we), e);
}

// ---------------- fused edge + scatter (batch-sorted, XCD-pinned) -----------
// XCD x (= blockIdx%8) processes batches x and x+8: their 0.5 MB q/k slices
// stay resident in that XCD's 4 MiB L2. 8 lanes/edge, coalesced 128B q/k
// loads, shfl_xor dot reduction (lane l owns head hh=2*(l&3)+(l>>2)).
// MLP weights packed as float4 [hh][m] with head stride 33 float4s: banks
// (4*hh+4m+i)%32 are disjoint across the 8 head groups -> conflict-free
// ds_read_b128, 32 LDS reads instead of 128.
__global__ __launch_bounds__(256) void edge_kernel(
        const float* __restrict__ qf, const float* __restrict__ kf,
        const int4* __restrict__ ebuf, const int* __restrict__ offs_row,
        const float* __restrict__ msW1, const float* __restrict__ msb1,
        const float* __restrict__ msW2, const float* __restrict__ msb2,
        int* __restrict__ cur_row, int* __restrict__ cur_col,
        float* __restrict__ entr, float* __restrict__ entc) {
    __shared__ float4 sPk[8 * 33];
    __shared__ float sB2[8];
    int t = threadIdx.x;
    {
        int h = t >> 5, m = t & 31;
        sPk[h * 33 + m] = make_float4(msW1[h * 64 + m], msW1[h * 64 + 32 + m],
                                      msb1[h * 32 + m], msW2[h * 32 + m]);
    }
    if (t < 8) sB2[t] = msb2[t];
    __syncthreads();

    int x = blockIdx.x & 7;
    int r0 = blockIdx.x >> 3;
    int a0 = offs_row[x << 10],       a1 = offs_row[(x + 1) << 10];
    int b0 = offs_row[(x + 8) << 10], b1 = offs_row[(x + 9) << 10];
    int nA = a1 - a0;
    int n = nA + (b1 - b0);

    int l = t & 7;          // lane within edge group
    int sub = t >> 3;       // edge slot within block (0..31)
    int hh = 2 * (l & 3) + (l >> 2);
    const float4* wp = &sPk[hh * 33];
    float bias2 = sB2[hh];

    for (int jb = r0 * 32; jb < n; jb += NBPX * 32) {
        int j = jb + sub;
        if (j < n) {
            int pos = (j < nA) ? (a0 + j) : (b0 + (j - nA));
            int4 rec = ebuf[pos];
            int row = rec.x, col = rec.y;
            float we = __int_as_float(rec.z);

            const float4* qp4 = (const float4*)(qf + (size_t)row * 128);
            const float4* kp4 = (const float4*)(kf + (size_t)col * 128);
            float p0, p1, p2, p3;
            {
                float4 a = qp4[l],      k4 = kp4[l];
                p0 = fmaf(a.x, k4.x, fmaf(a.y, k4.y, fmaf(a.z, k4.z, a.w * k4.w)));
            }
            {
                float4 a = qp4[8 + l],  k4 = kp4[8 + l];
                p1 = fmaf(a.x, k4.x, fmaf(a.y, k4.y, fmaf(a.z, k4.z, a.w * k4.w)));
            }
            {
                float4 a = qp4[16 + l], k4 = kp4[16 + l];
                p2 = fmaf(a.x, k4.x, fmaf(a.y, k4.y, fmaf(a.z, k4.z, a.w * k4.w)));
            }
            {
                float4 a = qp4[24 + l], k4 = kp4[24 + l];
                p3 = fmaf(a.x, k4.x, fmaf(a.y, k4.y, fmaf(a.z, k4.z, a.w * k4.w)));
            }
            p0 += __shfl_xor(p0, 1); p0 += __shfl_xor(p0, 2);
            p1 += __shfl_xor(p1, 1); p1 += __shfl_xor(p1, 2);
            p2 += __shfl_xor(p2, 1); p2 += __shfl_xor(p2, 2);
            p3 += __shfl_xor(p3, 1); p3 += __shfl_xor(p3, 2);

            int js = l & 3;
            float dot = js == 0 ? p0 : (js == 1 ? p1 : (js == 2 ? p2 : p3));
            float logit = dot * 0.25f;  // 1/sqrt(HD=16)

            float outv = bias2;
#pragma unroll 4
            for (int m = 0; m < MSS; m++) {
                float4 c = wp[m];       // {W1a, W1b, b1, W2} for (hh, m)
                float hid = fmaf(logit, c.x, fmaf(we, c.y, c.z));
                hid = fmaxf(hid, 0.f);
                outv = fmaf(hid, c.w, outv);
            }
            float ev = expf(10.0f * tanhf(outv));  // TANH_CLIP/TEMP, then exp
            __half evh = __float2half(ev);

            int pr = 0, pc = 0;
            if (l == 0) {
                pr = atomicAdd(&cur_row[row], 1);
                pc = atomicAdd(&cur_col[col], 1);
            }
            pr = __shfl(pr, 0, 8);
            pc = __shfl(pc, 0, 8);

            float* er = entr + (size_t)pr * ESTRIDE;
            float* ec = entc + (size_t)pc * ESTRIDE;
            ((__half*)er)[2 + hh] = evh;
            ((__half*)ec)[2 + hh] = evh;
            if (l == 0) {
                er[0] = __int_as_float(col);
                ec[0] = __int_as_float(row);
            }
        }
    }
}

// ---------------- dual group-softmax combine (XCD-pinned) -------------------
// XCD x handles batches x, x+8 for both sides -> v-slices (0.25 MB each)
// L2-resident. Entries stream; outputs sequential.
__global__ __launch_bounds__(128) void combine_kernel(
        const float* __restrict__ entr, const float* __restrict__ entc,
        const int* __restrict__ offs_row, const int* __restrict__ offs_col,
        const __half* __restrict__ v1h, const __half* __restrict__ v2h,
        float* __restrict__ row_heads, float* __restrict__ col_heads) {
    int x = blockIdx.x & 7;
    int r = blockIdx.x >> 3;        // 0..4095
    int which = r >> 10;            // 0,1 = row side; 2,3 = col side
    int sidx = r & 1023;
    int b = x + ((which & 1) << 3);
    int gl = (b << 10) + sidx;

    int t = threadIdx.x;  // t = h*16 + hd
    int h = t >> 4;
    const float* ent; const __half* vals; const int* offs; float* outp;
    if (which < 2) { ent = entr; vals = v2h; offs = offs_row; outp = row_heads; }
    else           { ent = entc; vals = v1h; offs = offs_col; outp = col_heads; }
    int s = offs[gl], e_ = offs[gl + 1];
    float acc = 0.f, den = 0.f;
#pragma unroll 4
    for (int i = s; i < e_; i++) {
        const float* en = ent + (size_t)i * ESTRIDE;
        int other = __float_as_int(en[0]);
        float ev = __half2float(((const __half*)en)[2 + h]);
        float v = __half2float(vals[(size_t)other * 128 + t]);
        acc = fmaf(ev, v, acc);
        den += ev;
    }
    outp[(size_t)gl * 128 + t] = acc / (den + 1e-9f);
}

extern "C" void kernel_launch(void* const* d_in, const int* in_sizes, int n_in,
                              void* d_out, int out_size, void* d_ws, size_t ws_size,
                              hipStream_t stream) {
    const float* x1   = (const float*)d_in[0];
    const float* x2   = (const float*)d_in[1];
    const int* b_idx  = (const int*)d_in[2];
    const int* s_idx  = (const int*)d_in[3];
    const int* p_idx  = (const int*)d_in[4];
    const float* w    = (const float*)d_in[5];
    const float* Wqv1 = (const float*)d_in[6];
    const float* Wkv2 = (const float*)d_in[7];
    const float* Wo1  = (const float*)d_in[8];
    const float* Wo2  = (const float*)d_in[9];
    const float* msW1 = (const float*)d_in[10];
    const float* msb1 = (const float*)d_in[11];
    const float* msW2 = (const float*)d_in[12];
    const float* msb2 = (const float*)d_in[13];
    float* out = (float*)d_out;

    // Workspace layout (~70 MiB).
    float* qf = (float*)d_ws;                         // 16384*128 f32 (8 MB)
    float* kf = qf + (size_t)NROW * 128;              // 16384*128 f32 (8 MB)
    __half* v1h = (__half*)(kf + (size_t)NCOL * 128); // 16384*128 f16 (4 MB)
    __half* v2h = v1h + (size_t)NROW * 128;           // 16384*128 f16 (4 MB)
    float* entr = (float*)(v2h + (size_t)NCOL * 128); // E*5 dwords (10.5 MB)
    float* entc = entr + (size_t)EE * ESTRIDE;        // E*5 dwords (10.5 MB)
    float* row_heads = entc + (size_t)EE * ESTRIDE;   // 16384*128 (8 MB)
    float* col_heads = row_heads + (size_t)NROW * 128;// (8 MB)
    int4* ebuf = (int4*)(col_heads + (size_t)NCOL * 128); // E int4 (8 MB)
    int* ip = (int*)(ebuf + EE);
    int* cnt = ip;       ip += 2 * NROW;              // cnt_row | cnt_col
    int* offs = ip;      ip += 2 * (NROW + 1);        // offs_row | offs_col
    int* cur = ip;       ip += 2 * NROW;              // cur_row | cur_col
    int* bcur = ip;      ip += 16;                    // batch cursors

    hipMemsetAsync(cnt, 0, 2 * NROW * sizeof(int), stream);

    proj_kernel<<<2 * (NROW / 16), 256, 0, stream>>>(
        x1, x2, Wqv1, Wkv2, b_idx, s_idx, p_idx,
        qf, kf, v1h, v2h, cnt, cnt + NROW);

    scan_kernel<<<2, 1024, 0, stream>>>(cnt, offs, cur, bcur);

    bucket_kernel<<<EE / 1024, 1024, 0, stream>>>(b_idx, s_idx, p_idx, w, bcur, ebuf);

    edge_kernel<<<8 * NBPX, 256, 0, stream>>>(
        qf, kf, ebuf, offs, msW1, msb1, msW2, msb2,
        cur, cur + NROW, entr, entc);

    combine_kernel<<<2 * NROW, 128, 0, stream>>>(
        entr, entc, offs, offs + (NROW + 1), v1h, v2h, row_heads, col_heads);

    outp_kernel<<<2 * (NROW / 16), 128, 0, stream>>>(row_heads, col_heads, Wo1, Wo2, out);
}

// Round 7
// 303.911 us; speedup vs baseline: 1.6961x; 1.0573x over previous
//
#include <hip/hip_runtime.h>
#include <hip/hip_fp16.h>
#include <math.h>

#define BB   16
#define SS   1024
#define PP   1024
#define HH   8
#define MSS  32
#define EE   524288
#define NROW (BB*SS)   /* 16384 */
#define NCOL (BB*PP)   /* 16384 */
#define ESTRIDE 5      /* dwords per edge entry: [0]=other id, [1..4]=8 x fp16 ev */
#define NBPX 2112      /* edge blocks per XCD slot */

// ============ tiled fp32 GEMM core: C_tile[64 x 128] = A[64 x 128] @ B[128 x 128-slice]
// 256 threads: tx = t&31 (col/4), ty = t>>5 (row group). Thread tile 8 rows x 4 cols:
// rows r = ty + 8i, cols c = 4*tx + j. acc4[8] float4.
// As: [64][128] fp32, stride 132 -> main-loop reads have 2 broadcast addrs/instr,
// banks 4*ty/4*ty+4 (conflict-free). Bs: [32][128] per k-chunk, lane-contiguous
// b128 reads (baseline pattern). Per k-quad/wave: ~12 b128 (~144cy) vs 256 VALU cy
// -> VALU-bound (old kernel: 1 ds_read_b32 per FMA, LDS-pipe 3x oversubscribed).
__device__ __forceinline__ void gemm_tile_core(
        const float* __restrict__ Arow,   // A + mb*64*128 (row-major, ld=128)
        const float* __restrict__ Bsrc,   // B (row-major, ld=ldb), col offset c0
        int ldb, int c0,
        float* As /*64*132*/, float* Bs /*32*128*/,
        float4 acc4[8], int t) {
    int tx = t & 31, ty = t >> 5;
    // stage A: 2048 float4s, 8 per thread
#pragma unroll
    for (int li = 0; li < 8; li++) {
        int idx = li * 256 + t;
        int r = idx >> 5, p = idx & 31;
        float4 v = *(const float4*)(Arow + r * 128 + 4 * p);
        *(float4*)&As[r * 132 + 4 * p] = v;
    }
#pragma unroll
    for (int i = 0; i < 8; i++) acc4[i] = make_float4(0.f, 0.f, 0.f, 0.f);

    for (int kc = 0; kc < 4; kc++) {
        __syncthreads();
        // stage B chunk: 32 k x 128 c, 4 float4 per thread
#pragma unroll
        for (int li = 0; li < 4; li++) {
            int idx = li * 256 + t;
            int kk = idx >> 5, p = idx & 31;
            float4 v = *(const float4*)(Bsrc + (size_t)(kc * 32 + kk) * ldb + c0 + 4 * p);
            *(float4*)&Bs[kk * 128 + 4 * p] = v;
        }
        __syncthreads();
#pragma unroll
        for (int kq = 0; kq < 8; kq++) {
            float4 a4[8];
#pragma unroll
            for (int i = 0; i < 8; i++)
                a4[i] = *(const float4*)&As[(ty + 8 * i) * 132 + kc * 32 + kq * 4];
#pragma unroll
            for (int kk = 0; kk < 4; kk++) {
                float4 b4 = *(const float4*)&Bs[(kq * 4 + kk) * 128 + 4 * tx];
#pragma unroll
                for (int i = 0; i < 8; i++) {
                    float av = ((const float*)&a4[i])[kk];
                    acc4[i].x = fmaf(av, b4.x, acc4[i].x);
                    acc4[i].y = fmaf(av, b4.y, acc4[i].y);
                    acc4[i].z = fmaf(av, b4.z, acc4[i].z);
                    acc4[i].w = fmaf(av, b4.w, acc4[i].w);
                }
            }
        }
    }
}

// ---------------- projection + fused edge-count histogram -------------------
// grid 1024: bid = matrix*512 + ct*256 + mb. ct0 -> qf/kf fp32; ct1 -> v fp16.
__global__ __launch_bounds__(256) void proj_kernel(
        const float* __restrict__ x1, const float* __restrict__ x2,
        const float* __restrict__ Wqv1, const float* __restrict__ Wkv2,
        const int* __restrict__ b_idx, const int* __restrict__ s_idx,
        const int* __restrict__ p_idx,
        float* __restrict__ qf, float* __restrict__ kf,
        __half* __restrict__ v1h, __half* __restrict__ v2h,
        int* __restrict__ cnt_row, int* __restrict__ cnt_col) {
    __shared__ float As[64 * 132];
    __shared__ float Bs[32 * 128];
    int t = threadIdx.x;

    // fused histogram: 262144 threads x 2 edges
    {
        int gid = blockIdx.x * 256 + t;
#pragma unroll
        for (int q = 0; q < 2; q++) {
            int e = gid + q * 262144;
            int b = b_idx[e];
            atomicAdd(&cnt_row[b * SS + s_idx[e]], 1);
            atomicAdd(&cnt_col[b * PP + p_idx[e]], 1);
        }
    }

    int bid = blockIdx.x;
    int matrix = bid >> 9;
    int ct = (bid >> 8) & 1;
    int mb = bid & 255;
    const float* A  = matrix ? x2 : x1;
    const float* Bm = matrix ? Wkv2 : Wqv1;

    float4 acc4[8];
    gemm_tile_core(A + (size_t)mb * 64 * 128, Bm, 256, ct * 128, As, Bs, acc4, t);

    int tx = t & 31, ty = t >> 5;
    if (ct == 0) {
        float* Cq = matrix ? kf : qf;
#pragma unroll
        for (int i = 0; i < 8; i++) {
            int row = mb * 64 + ty + 8 * i;
            *(float4*)(Cq + (size_t)row * 128 + 4 * tx) = acc4[i];
        }
    } else {
        __half* Cv = matrix ? v2h : v1h;
#pragma unroll
        for (int i = 0; i < 8; i++) {
            int row = mb * 64 + ty + 8 * i;
            __half2* p = (__half2*)(Cv + (size_t)row * 128 + 4 * tx);
            p[0] = __halves2half2(__float2half(acc4[i].x), __float2half(acc4[i].y));
            p[1] = __halves2half2(__float2half(acc4[i].z), __float2half(acc4[i].w));
        }
    }
}

// ---------------- output GEMMs: h1 = rh@Wo1, h2 = ch@Wo2 --------------------
// grid 512: bid = matrix*256 + mb.
__global__ __launch_bounds__(256) void outp_kernel(
        const float* __restrict__ rh, const float* __restrict__ ch,
        const float* __restrict__ Wo1, const float* __restrict__ Wo2,
        float* __restrict__ out) {
    __shared__ float As[64 * 132];
    __shared__ float Bs[32 * 128];
    int t = threadIdx.x;
    int bid = blockIdx.x;
    int matrix = bid >> 8;
    int mb = bid & 255;
    const float* A  = matrix ? ch : rh;
    const float* Bm = matrix ? Wo2 : Wo1;
    float* C = out + (size_t)matrix * NROW * 128;

    float4 acc4[8];
    gemm_tile_core(A + (size_t)mb * 64 * 128, Bm, 128, 0, As, Bs, acc4, t);

    int tx = t & 31, ty = t >> 5;
#pragma unroll
    for (int i = 0; i < 8; i++) {
        int row = mb * 64 + ty + 8 * i;
        *(float4*)(C + (size_t)row * 128 + 4 * tx) = acc4[i];
    }
}

// ------- scan: counts -> offsets[16385] + cursor seed + batch offsets -------
__global__ __launch_bounds__(1024) void scan_kernel(const int* __restrict__ cnt,
                                                    int* __restrict__ offs,
                                                    int* __restrict__ cur,
                                                    int* __restrict__ bcur) {
    const int n = NROW;
    const int* c = cnt + (size_t)blockIdx.x * n;
    int* o = offs + (size_t)blockIdx.x * (n + 1);
    int* cu = cur + (size_t)blockIdx.x * n;
    __shared__ int sdata[1024];
    int t = threadIdx.x;
    int base = t * 16;
    int loc[16];
    int run = 0;
#pragma unroll
    for (int i = 0; i < 16; i++) { loc[i] = run; run += c[base + i]; }
    sdata[t] = run;
    __syncthreads();
    for (int st = 1; st < 1024; st <<= 1) {
        int v = (t >= st) ? sdata[t - st] : 0;
        __syncthreads();
        sdata[t] += v;
        __syncthreads();
    }
    int excl = sdata[t] - run;
#pragma unroll
    for (int i = 0; i < 16; i++) {
        int idx = base + i;
        int val = excl + loc[i];
        o[idx] = val;
        cu[idx] = val;
        if (blockIdx.x == 0 && (idx & 1023) == 0) bcur[idx >> 10] = val;
    }
    if (t == 1023) o[n] = sdata[1023];
}

// ---------------- batch bucket-sort of edges --------------------------------
__global__ __launch_bounds__(1024) void bucket_kernel(
        const int* __restrict__ b_idx, const int* __restrict__ s_idx,
        const int* __restrict__ p_idx, const float* __restrict__ w,
        int* __restrict__ bcur, int4* __restrict__ ebuf) {
    __shared__ int lcnt[16], lbase[16];
    int t = threadIdx.x;
    if (t < 16) lcnt[t] = 0;
    __syncthreads();
    int e = blockIdx.x * 1024 + t;
    int b = b_idx[e];
    int row = b * SS + s_idx[e];
    int col = b * PP + p_idx[e];
    float we = w[e];
    int myloc = atomicAdd(&lcnt[b], 1);
    __syncthreads();
    if (t < 16) lbase[t] = atomicAdd(&bcur[t], lcnt[t]);
    __syncthreads();
    ebuf[lbase[b] + myloc] = make_int4(row, col, __float_as_int(we), e);
}

// ---------------- fused edge + scatter (batch-sorted, XCD-pinned) -----------
__global__ __launch_bounds__(256) void edge_kernel(
        const float* __restrict__ qf, const float* __restrict__ kf,
        const int4* __restrict__ ebuf, const int* __restrict__ offs_row,
        const float* __restrict__ msW1, const float* __restrict__ msb1,
        const float* __restrict__ msW2, const float* __restrict__ msb2,
        int* __restrict__ cur_row, int* __restrict__ cur_col,
        float* __restrict__ entr, float* __restrict__ entc) {
    __shared__ float4 sPk[8 * 33];
    __shared__ float sB2[8];
    int t = threadIdx.x;
    {
        int h = t >> 5, m = t & 31;
        sPk[h * 33 + m] = make_float4(msW1[h * 64 + m], msW1[h * 64 + 32 + m],
                                      msb1[h * 32 + m], msW2[h * 32 + m]);
    }
    if (t < 8) sB2[t] = msb2[t];
    __syncthreads();

    int x = blockIdx.x & 7;
    int r0 = blockIdx.x >> 3;
    int a0 = offs_row[x << 10],       a1 = offs_row[(x + 1) << 10];
    int b0 = offs_row[(x + 8) << 10], b1 = offs_row[(x + 9) << 10];
    int nA = a1 - a0;
    int n = nA + (b1 - b0);

    int l = t & 7;
    int sub = t >> 3;
    int hh = 2 * (l & 3) + (l >> 2);
    const float4* wp = &sPk[hh * 33];
    float bias2 = sB2[hh];

    for (int jb = r0 * 32; jb < n; jb += NBPX * 32) {
        int j = jb + sub;
        if (j < n) {
            int pos = (j < nA) ? (a0 + j) : (b0 + (j - nA));
            int4 rec = ebuf[pos];
            int row = rec.x, col = rec.y;
            float we = __int_as_float(rec.z);

            const float4* qp4 = (const float4*)(qf + (size_t)row * 128);
            const float4* kp4 = (const float4*)(kf + (size_t)col * 128);
            float p0, p1, p2, p3;
            {
                float4 a = qp4[l],      k4 = kp4[l];
                p0 = fmaf(a.x, k4.x, fmaf(a.y, k4.y, fmaf(a.z, k4.z, a.w * k4.w)));
            }
            {
                float4 a = qp4[8 + l],  k4 = kp4[8 + l];
                p1 = fmaf(a.x, k4.x, fmaf(a.y, k4.y, fmaf(a.z, k4.z, a.w * k4.w)));
            }
            {
                float4 a = qp4[16 + l], k4 = kp4[16 + l];
                p2 = fmaf(a.x, k4.x, fmaf(a.y, k4.y, fmaf(a.z, k4.z, a.w * k4.w)));
            }
            {
                float4 a = qp4[24 + l], k4 = kp4[24 + l];
                p3 = fmaf(a.x, k4.x, fmaf(a.y, k4.y, fmaf(a.z, k4.z, a.w * k4.w)));
            }
            p0 += __shfl_xor(p0, 1); p0 += __shfl_xor(p0, 2);
            p1 += __shfl_xor(p1, 1); p1 += __shfl_xor(p1, 2);
            p2 += __shfl_xor(p2, 1); p2 += __shfl_xor(p2, 2);
            p3 += __shfl_xor(p3, 1); p3 += __shfl_xor(p3, 2);

            int js = l & 3;
            float dot = js == 0 ? p0 : (js == 1 ? p1 : (js == 2 ? p2 : p3));
            float logit = dot * 0.25f;

            float outv = bias2;
#pragma unroll 4
            for (int m = 0; m < MSS; m++) {
                float4 c = wp[m];
                float hid = fmaf(logit, c.x, fmaf(we, c.y, c.z));
                hid = fmaxf(hid, 0.f);
                outv = fmaf(hid, c.w, outv);
            }
            float ev = expf(10.0f * tanhf(outv));
            __half evh = __float2half(ev);

            int pr = 0, pc = 0;
            if (l == 0) {
                pr = atomicAdd(&cur_row[row], 1);
                pc = atomicAdd(&cur_col[col], 1);
            }
            pr = __shfl(pr, 0, 8);
            pc = __shfl(pc, 0, 8);

            float* er = entr + (size_t)pr * ESTRIDE;
            float* ec = entc + (size_t)pc * ESTRIDE;
            ((__half*)er)[2 + hh] = evh;
            ((__half*)ec)[2 + hh] = evh;
            if (l == 0) {
                er[0] = __int_as_float(col);
                ec[0] = __int_as_float(row);
            }
        }
    }
}

// ---------------- dual group-softmax combine (XCD-pinned) -------------------
__global__ __launch_bounds__(128) void combine_kernel(
        const float* __restrict__ entr, const float* __restrict__ entc,
        const int* __restrict__ offs_row, const int* __restrict__ offs_col,
        const __half* __restrict__ v1h, const __half* __restrict__ v2h,
        float* __restrict__ row_heads, float* __restrict__ col_heads) {
    int x = blockIdx.x & 7;
    int r = blockIdx.x >> 3;
    int which = r >> 10;
    int sidx = r & 1023;
    int b = x + ((which & 1) << 3);
    int gl = (b << 10) + sidx;

    int t = threadIdx.x;
    int h = t >> 4;
    const float* ent; const __half* vals; const int* offs; float* outp;
    if (which < 2) { ent = entr; vals = v2h; offs = offs_row; outp = row_heads; }
    else           { ent = entc; vals = v1h; offs = offs_col; outp = col_heads; }
    int s = offs[gl], e_ = offs[gl + 1];
    float acc = 0.f, den = 0.f;
#pragma unroll 4
    for (int i = s; i < e_; i++) {
        const float* en = ent + (size_t)i * ESTRIDE;
        int other = __float_as_int(en[0]);
        float ev = __half2float(((const __half*)en)[2 + h]);
        float v = __half2float(vals[(size_t)other * 128 + t]);
        acc = fmaf(ev, v, acc);
        den += ev;
    }
    outp[(size_t)gl * 128 + t] = acc / (den + 1e-9f);
}

extern "C" void kernel_launch(void* const* d_in, const int* in_sizes, int n_in,
                              void* d_out, int out_size, void* d_ws, size_t ws_size,
                              hipStream_t stream) {
    const float* x1   = (const float*)d_in[0];
    const float* x2   = (const float*)d_in[1];
    const int* b_idx  = (const int*)d_in[2];
    const int* s_idx  = (const int*)d_in[3];
    const int* p_idx  = (const int*)d_in[4];
    const float* w    = (const float*)d_in[5];
    const float* Wqv1 = (const float*)d_in[6];
    const float* Wkv2 = (const float*)d_in[7];
    const float* Wo1  = (const float*)d_in[8];
    const float* Wo2  = (const float*)d_in[9];
    const float* msW1 = (const float*)d_in[10];
    const float* msb1 = (const float*)d_in[11];
    const float* msW2 = (const float*)d_in[12];
    const float* msb2 = (const float*)d_in[13];
    float* out = (float*)d_out;

    // Workspace layout (~70 MiB).
    float* qf = (float*)d_ws;                         // 16384*128 f32 (8 MB)
    float* kf = qf + (size_t)NROW * 128;              // 16384*128 f32 (8 MB)
    __half* v1h = (__half*)(kf + (size_t)NCOL * 128); // 16384*128 f16 (4 MB)
    __half* v2h = v1h + (size_t)NROW * 128;           // 16384*128 f16 (4 MB)
    float* entr = (float*)(v2h + (size_t)NCOL * 128); // E*5 dwords (10.5 MB)
    float* entc = entr + (size_t)EE * ESTRIDE;        // E*5 dwords (10.5 MB)
    float* row_heads = entc + (size_t)EE * ESTRIDE;   // 16384*128 (8 MB)
    float* col_heads = row_heads + (size_t)NROW * 128;// (8 MB)
    int4* ebuf = (int4*)(col_heads + (size_t)NCOL * 128); // E int4 (8 MB)
    int* ip = (int*)(ebuf + EE);
    int* cnt = ip;       ip += 2 * NROW;              // cnt_row | cnt_col
    int* offs = ip;      ip += 2 * (NROW + 1);        // offs_row | offs_col
    int* cur = ip;       ip += 2 * NROW;              // cur_row | cur_col
    int* bcur = ip;      ip += 16;                    // batch cursors

    hipMemsetAsync(cnt, 0, 2 * NROW * sizeof(int), stream);

    proj_kernel<<<1024, 256, 0, stream>>>(
        x1, x2, Wqv1, Wkv2, b_idx, s_idx, p_idx,
        qf, kf, v1h, v2h, cnt, cnt + NROW);

    scan_kernel<<<2, 1024, 0, stream>>>(cnt, offs, cur, bcur);

    bucket_kernel<<<EE / 1024, 1024, 0, stream>>>(b_idx, s_idx, p_idx, w, bcur, ebuf);

    edge_kernel<<<8 * NBPX, 256, 0, stream>>>(
        qf, kf, ebuf, offs, msW1, msb1, msW2, msb2,
        cur, cur + NROW, entr, entc);

    combine_kernel<<<2 * NROW, 128, 0, stream>>>(
        entr, entc, offs, offs + (NROW + 1), v1h, v2h, row_heads, col_heads);

    outp_kernel<<<512, 256, 0, stream>>>(row_heads, col_heads, Wo1, Wo2, out);
}